// Round 1
// baseline (422.345 us; speedup 1.0000x reference)
//
#include <hip/hip_runtime.h>
#include <hip/hip_bf16.h>

#define EMBED 768
#define HEADS 12
#define HD 64
#define BATCH 4
#define SEQ 2048
#define M_TOK (BATCH*SEQ)   // 8192
#define N_QKV (3*EMBED)     // 2304

typedef short bf8 __attribute__((ext_vector_type(8)));
typedef float f4  __attribute__((ext_vector_type(4)));

static __device__ inline unsigned short f2bf(float f) {
    unsigned int x = __float_as_uint(f);
    unsigned int r = (x + 0x7fffu + ((x >> 16) & 1u)) >> 16;   // RNE
    return (unsigned short)r;
}

// ---------------- fp32 -> bf16 elementwise ----------------
__global__ void cvt_f32_bf16(const float* __restrict__ in,
                             unsigned short* __restrict__ out, int n) {
    int i = (blockIdx.x * blockDim.x + threadIdx.x) * 4;
    if (i < n) {
        float4 v = *reinterpret_cast<const float4*>(in + i);
        ushort4 o;
        o.x = f2bf(v.x); o.y = f2bf(v.y); o.z = f2bf(v.z); o.w = f2bf(v.w);
        *reinterpret_cast<ushort4*>(out + i) = o;
    }
}

// ---------------- fp32 [R][C] -> bf16 [C][R] transpose ----------------
__global__ void transpose_f32_bf16(const float* __restrict__ in,
                                   unsigned short* __restrict__ out, int R, int C) {
    __shared__ float tile[32][33];
    int c0 = blockIdx.x * 32, r0 = blockIdx.y * 32;
    int tx = threadIdx.x, ty = threadIdx.y;      // 32 x 8
    for (int i = 0; i < 32; i += 8)
        tile[ty + i][tx] = in[(size_t)(r0 + ty + i) * C + c0 + tx];
    __syncthreads();
    for (int i = 0; i < 32; i += 8)
        out[(size_t)(c0 + ty + i) * R + r0 + tx] = f2bf(tile[tx][ty + i]);
}

// ---------------- bf16 GEMM: C[M][N] = A[M][K] * BT[N][K]^T + bias ----------------
// 128x128 tile, 256 threads (4 waves, 2x2 of 64x64), mfma_f32_16x16x32_bf16
template<int OUT_MODE>  // 0: bf16 out, 1: fp32 out
__global__ __launch_bounds__(256) void gemm_bf16(
    const unsigned short* __restrict__ A,
    const unsigned short* __restrict__ BT,
    const float* __restrict__ bias,
    void* __restrict__ Cout, int M, int N, int K)
{
    const int LDA = 40;  // 32 + 8 halfword pad
    __shared__ unsigned short a_lds[128 * 40];
    __shared__ unsigned short b_lds[128 * 40];
    int tid  = threadIdx.x;
    int lane = tid & 63, w = tid >> 6;
    int quad = lane >> 4, cc = lane & 15;
    int m0 = blockIdx.x * 128, n0 = blockIdx.y * 128;
    int wr = w >> 1, wc = w & 1;
    int mb = wr * 64, nb = wc * 64;
    f4 acc[4][4] = {};
    for (int k0 = 0; k0 < K; k0 += 32) {
        __syncthreads();
        for (int p = 0; p < 2; ++p) {
            int li  = p * 256 + tid;          // 0..511
            int row = li >> 2, ch = li & 3;   // 128 rows x 4 chunks of 8
            *reinterpret_cast<uint4*>(&a_lds[row * LDA + ch * 8]) =
                *reinterpret_cast<const uint4*>(A + (size_t)(m0 + row) * K + k0 + ch * 8);
            *reinterpret_cast<uint4*>(&b_lds[row * LDA + ch * 8]) =
                *reinterpret_cast<const uint4*>(BT + (size_t)(n0 + row) * K + k0 + ch * 8);
        }
        __syncthreads();
        bf8 af[4], bfv[4];
        for (int mi = 0; mi < 4; ++mi)
            af[mi] = *reinterpret_cast<const bf8*>(&a_lds[(mb + mi * 16 + cc) * LDA + quad * 8]);
        for (int ni = 0; ni < 4; ++ni)
            bfv[ni] = *reinterpret_cast<const bf8*>(&b_lds[(nb + ni * 16 + cc) * LDA + quad * 8]);
        for (int mi = 0; mi < 4; ++mi)
            for (int ni = 0; ni < 4; ++ni)
                acc[mi][ni] = __builtin_amdgcn_mfma_f32_16x16x32_bf16(af[mi], bfv[ni], acc[mi][ni], 0, 0, 0);
    }
    for (int mi = 0; mi < 4; ++mi)
        for (int ni = 0; ni < 4; ++ni) {
            int gn = n0 + nb + ni * 16 + cc;
            float bv = bias[gn];
            for (int r = 0; r < 4; ++r) {
                int gm = m0 + mb + mi * 16 + quad * 4 + r;
                float v = acc[mi][ni][r] + bv;
                if (OUT_MODE == 0)
                    ((unsigned short*)Cout)[(size_t)gm * N + gn] = f2bf(v);
                else
                    ((float*)Cout)[(size_t)gm * N + gn] = v;
            }
        }
}

// ---------------- flash attention ----------------
// grid: (SEQ/64, HEADS, BATCH), 256 threads. Wave w handles q rows [q0+16w, q0+16w+16).
__global__ __launch_bounds__(256) void attn_kernel(
    const unsigned short* __restrict__ qkv,   // [B*T][2304] bf16 (q|k|v each [H][64])
    unsigned short* __restrict__ out)         // [B*T][768] bf16
{
    const int LDK = 72;  // 64 + 8 pad
    __shared__ unsigned short k_lds[64 * 72];
    __shared__ unsigned short vt_lds[64 * 72];
    __shared__ unsigned short p_lds[4 * 16 * 72];
    int tid  = threadIdx.x;
    int lane = tid & 63, w = tid >> 6;
    int quad = lane >> 4, cc = lane & 15;
    int qt = blockIdx.x, h = blockIdx.y, b = blockIdx.z;
    int q0 = qt * 64;
    size_t base = (size_t)b * SEQ * 2304;

    // Q fragments resident in registers (A-layout: m=cc, k=quad*8+j [+32])
    bf8 qf[2];
    {
        const unsigned short* qp = qkv + base + (size_t)(q0 + w * 16 + cc) * 2304 + h * 64;
        qf[0] = *reinterpret_cast<const bf8*>(qp + quad * 8);
        qf[1] = *reinterpret_cast<const bf8*>(qp + 32 + quad * 8);
    }
    float m_prev[4], l_run[4];
    f4 o[4] = {};
    for (int r = 0; r < 4; ++r) { m_prev[r] = -3.0e38f; l_run[r] = 0.f; }
    const float SL2E = 0.125f * 1.44269504088896340736f;  // scale * log2(e)

    for (int kt = 0; kt < SEQ; kt += 64) {
        __syncthreads();
        // stage K tile row-major and V tile transposed
        for (int p = 0; p < 2; ++p) {
            int li  = p * 256 + tid;           // 0..511
            int row = li >> 3, ch = li & 7;    // 64 rows x 8 chunks of 8
            const unsigned short* kp = qkv + base + (size_t)(kt + row) * 2304 + 768 + h * 64 + ch * 8;
            *reinterpret_cast<uint4*>(&k_lds[row * LDK + ch * 8]) =
                *reinterpret_cast<const uint4*>(kp);
            uint4 vv = *reinterpret_cast<const uint4*>(kp + 768);  // v = k + 768 cols
            const unsigned short* vs = reinterpret_cast<const unsigned short*>(&vv);
            for (int j = 0; j < 8; ++j)
                vt_lds[(ch * 8 + j) * LDK + row] = vs[j];
        }
        __syncthreads();
        // S = Q K^T  (B-frag: K[n=nt*16+cc][k], contiguous rows of k_lds)
        f4 s[4];
        for (int nt = 0; nt < 4; ++nt) {
            bf8 b0 = *reinterpret_cast<const bf8*>(&k_lds[(nt * 16 + cc) * LDK + quad * 8]);
            bf8 b1 = *reinterpret_cast<const bf8*>(&k_lds[(nt * 16 + cc) * LDK + 32 + quad * 8]);
            f4 z = {};
            z = __builtin_amdgcn_mfma_f32_16x16x32_bf16(qf[0], b0, z, 0, 0, 0);
            z = __builtin_amdgcn_mfma_f32_16x16x32_bf16(qf[1], b1, z, 0, 0, 0);
            s[nt] = z;
        }
        // online softmax; row r_global = quad*4+r, cols spread over 16 lanes of the quad
        float pv[4][4];
        for (int r = 0; r < 4; ++r) {
            float sc0 = s[0][r] * SL2E, sc1 = s[1][r] * SL2E;
            float sc2 = s[2][r] * SL2E, sc3 = s[3][r] * SL2E;
            float mx = fmaxf(fmaxf(sc0, sc1), fmaxf(sc2, sc3));
            for (int off = 1; off < 16; off <<= 1)
                mx = fmaxf(mx, __shfl_xor(mx, off));
            float mn = fmaxf(m_prev[r], mx);
            float alpha = exp2f(m_prev[r] - mn);
            float p0 = exp2f(sc0 - mn), p1 = exp2f(sc1 - mn);
            float p2 = exp2f(sc2 - mn), p3 = exp2f(sc3 - mn);
            float ps = p0 + p1 + p2 + p3;
            for (int off = 1; off < 16; off <<= 1)
                ps += __shfl_xor(ps, off);
            l_run[r] = l_run[r] * alpha + ps;
            m_prev[r] = mn;
            for (int nt = 0; nt < 4; ++nt) o[nt][r] *= alpha;
            pv[0][r] = p0; pv[1][r] = p1; pv[2][r] = p2; pv[3][r] = p3;
        }
        // P: C-layout -> LDS -> A-layout (per-wave region)
        int pbase = w * 16 * LDK;
        for (int nt = 0; nt < 4; ++nt)
            for (int r = 0; r < 4; ++r)
                p_lds[pbase + (quad * 4 + r) * LDK + nt * 16 + cc] = f2bf(pv[nt][r]);
        __syncthreads();
        // O += P V   (A-frag: P[m=cc][k=ks*32+quad*8+j]; B-frag: VT rows)
        for (int ks = 0; ks < 2; ++ks) {
            bf8 af = *reinterpret_cast<const bf8*>(&p_lds[pbase + cc * LDK + ks * 32 + quad * 8]);
            for (int nt = 0; nt < 4; ++nt) {
                bf8 bv = *reinterpret_cast<const bf8*>(&vt_lds[(nt * 16 + cc) * LDK + ks * 32 + quad * 8]);
                o[nt] = __builtin_amdgcn_mfma_f32_16x16x32_bf16(af, bv, o[nt], 0, 0, 0);
            }
        }
    }
    // epilogue: normalize and store bf16
    for (int r = 0; r < 4; ++r) {
        float inv = 1.0f / l_run[r];
        int q = q0 + w * 16 + quad * 4 + r;
        size_t ob = ((size_t)b * SEQ + q) * 768 + h * 64;
        for (int nt = 0; nt < 4; ++nt)
            out[ob + nt * 16 + cc] = f2bf(o[nt][r] * inv);
    }
}

extern "C" void kernel_launch(void* const* d_in, const int* in_sizes, int n_in,
                              void* d_out, int out_size, void* d_ws, size_t ws_size,
                              hipStream_t stream) {
    const float* x      = (const float*)d_in[0];
    const float* w_qkv  = (const float*)d_in[1];
    const float* b_qkv  = (const float*)d_in[2];
    const float* w_proj = (const float*)d_in[3];
    const float* b_proj = (const float*)d_in[4];
    float* out = (float*)d_out;
    char* ws = (char*)d_ws;
    // workspace layout (bytes): all 256-aligned
    unsigned short* qkv    = (unsigned short*)(ws);                 // 8192*2304*2 = 37748736
    unsigned short* aout   = (unsigned short*)(ws + 37748736);      // 8192*768*2  = 12582912
    unsigned short* xbf    = (unsigned short*)(ws + 50331648);      // 8192*768*2  = 12582912
    unsigned short* wqkvT  = (unsigned short*)(ws + 62914560);      // 2304*768*2  = 3538944
    unsigned short* wprojT = (unsigned short*)(ws + 66453504);      // 768*768*2   = 1179648

    cvt_f32_bf16<<<(M_TOK * EMBED) / 1024, 256, 0, stream>>>(x, xbf, M_TOK * EMBED);
    transpose_f32_bf16<<<dim3(N_QKV / 32, EMBED / 32), dim3(32, 8), 0, stream>>>(w_qkv, wqkvT, EMBED, N_QKV);
    transpose_f32_bf16<<<dim3(EMBED / 32, EMBED / 32), dim3(32, 8), 0, stream>>>(w_proj, wprojT, EMBED, EMBED);
    gemm_bf16<0><<<dim3(M_TOK / 128, N_QKV / 128), 256, 0, stream>>>(xbf, wqkvT, b_qkv, qkv, M_TOK, N_QKV, EMBED);
    attn_kernel<<<dim3(SEQ / 64, HEADS, BATCH), 256, 0, stream>>>(qkv, aout);
    gemm_bf16<1><<<dim3(M_TOK / 128, EMBED / 128), 256, 0, stream>>>(aout, wprojT, b_proj, out, M_TOK, EMBED, EMBED);
}